// Round 3
// baseline (642.220 us; speedup 1.0000x reference)
//
#include <hip/hip_runtime.h>

typedef unsigned short u16;
typedef __attribute__((ext_vector_type(8))) short bf16x8;
typedef __attribute__((ext_vector_type(4))) float f32x4;

#define NTOK 32768
#define CC 512
#define HH 8
#define LL 64
#define NBLK 512
#define MTOK 65536

__device__ __forceinline__ u16 f2bf(float f) {
    unsigned int u = __float_as_uint(f);
    unsigned int r = u + 0x7fffu + ((u >> 16) & 1u);
    return (u16)(r >> 16);
}
__device__ __forceinline__ float bf2f(u16 h) {
    return __uint_as_float(((unsigned int)h) << 16);
}
__device__ __forceinline__ bf16x8 bc8(uint4 v) {
    return __builtin_bit_cast(bf16x8, v);
}
__device__ __forceinline__ void dma16(const u16* g, u16* l) {
    __builtin_amdgcn_global_load_lds((const __attribute__((address_space(1))) void*)g,
                                     (__attribute__((address_space(3))) void*)l, 16, 0, 0);
}

// ---------------- kernel 0: x fp32 -> bf16, fused g_block GEMV ----------------
__global__ __launch_bounds__(256) void convert_gblock_kernel(const float* __restrict__ x,
                                                             u16* __restrict__ xbf,
                                                             const float* __restrict__ w_blk,
                                                             const float* __restrict__ b_blk,
                                                             float* __restrict__ gbl) {
    __shared__ float wbs[4608];
    int tid = threadIdx.x;
    for (int i = tid; i < 4096; i += 256) wbs[i + (i >> 6)] = w_blk[i];
    size_t tok = (size_t)blockIdx.x * 4 + (tid >> 6);
    int lane = tid & 63;
    int c0 = lane * 8;
    const float4* p = (const float4*)(x + tok * CC + c0);
    float4 a = p[0], b = p[1];
    uint4 o;
    o.x = (unsigned)f2bf(a.x) | ((unsigned)f2bf(a.y) << 16);
    o.y = (unsigned)f2bf(a.z) | ((unsigned)f2bf(a.w) << 16);
    o.z = (unsigned)f2bf(b.x) | ((unsigned)f2bf(b.y) << 16);
    o.w = (unsigned)f2bf(b.z) | ((unsigned)f2bf(b.w) << 16);
    *(uint4*)(xbf + tok * CC + c0) = o;
    float xv[8] = {a.x, a.y, a.z, a.w, b.x, b.y, b.z, b.w};
    __syncthreads();
    float acc[8];
#pragma unroll
    for (int h = 0; h < 8; ++h) acc[h] = 0.f;
#pragma unroll
    for (int j = 0; j < 8; ++j) {
        const float* wr = &wbs[(c0 + j) * 8 + lane];
#pragma unroll
        for (int h = 0; h < 8; ++h) acc[h] += xv[j] * wr[h];
    }
#pragma unroll
    for (int h = 0; h < 8; ++h) {
#pragma unroll
        for (int off = 1; off < 64; off <<= 1) acc[h] += __shfl_xor(acc[h], off);
    }
    float v = acc[0];
#pragma unroll
    for (int h = 1; h < 8; ++h) v = (lane == h) ? acc[h] : v;
    if (lane < 8) gbl[tok * 8 + lane] = 1.f / (1.f + __expf(-(v + b_blk[lane])));
}

// ---------------- kernel 1: transpose fp32 [K][Nn] -> bf16 [Nn][K] ----------------
__global__ __launch_bounds__(256) void transpose_bf16_kernel(const float* __restrict__ in,
                                                             u16* __restrict__ out,
                                                             int K, int Nn) {
    __shared__ float tile[32][33];
    int n0 = blockIdx.x * 32, k0 = blockIdx.y * 32;
    int tx = threadIdx.x & 31, ty = threadIdx.x >> 5;
#pragma unroll
    for (int i = 0; i < 4; ++i)
        tile[ty + i * 8][tx] = in[(size_t)(k0 + ty + i * 8) * Nn + n0 + tx];
    __syncthreads();
#pragma unroll
    for (int i = 0; i < 4; ++i)
        out[(size_t)(n0 + ty + i * 8) * K + k0 + tx] = f2bf(tile[tx][ty + i * 8]);
}

// ---------------- kernel 2: sbias2/gate2 in MFMA C-fragment layout ----------------
__global__ __launch_bounds__(256) void gate_sbias_kernel(const int* __restrict__ mask,
                                                         const float* __restrict__ edge,
                                                         const float* __restrict__ w1,
                                                         const float* __restrict__ b1,
                                                         const float* __restrict__ w2,
                                                         const float* __restrict__ b2,
                                                         u16* __restrict__ gate2,
                                                         u16* __restrict__ sbias2) {
    __shared__ float w1s[64], b1s[16], w2s[128], b2s[8];
    __shared__ int nds[16];
    int t = threadIdx.x;
    int nb = blockIdx.x >> 2;
    int qt = blockIdx.x & 3;
    if (t < 64) w1s[t] = w1[t];
    if (t < 16) b1s[t] = b1[t];
    if (t < 128) w2s[t] = w2[t];
    if (t < 8) b2s[t] = b2[t];
    if (t >= 128 && t < 144) {
        int q = qt * 16 + (t - 128);
        int s = 0;
        const int* mr = mask + (size_t)(nb * 64 + q) * 64;
#pragma unroll 8
        for (int k = 0; k < 64; ++k) s += mr[k];
        nds[t - 128] = (s < 1) ? 1 : 0;
    }
    __syncthreads();
#pragma unroll 1
    for (int it = 0; it < 4; ++it) {
        int p = it * 256 + t;
        int ql = p >> 6, k = p & 63;
        int q = qt * 16 + ql;
        int pk = (k & 15) * 4 + (k >> 4);
        int mv = mask[(size_t)(nb * 64 + q) * 64 + k];
        float e0, e1, e2, e3;
        if (q == k) {
            mv = max(mv, nds[ql]);
            e0 = e1 = e2 = 0.f;
            e3 = 1.f;
        } else {
            const float* ep = edge + ((size_t)(nb * 64 + q) * 64 + k) * 4;
            e0 = ep[0]; e1 = ep[1]; e2 = ep[2]; e3 = ep[3];
        }
        sbias2[(size_t)(nb * 64 + q) * 64 + pk] = f2bf(mv ? e3 : -1e30f);
        float g[8];
#pragma unroll
        for (int hh = 0; hh < 8; ++hh) g[hh] = b2s[hh];
#pragma unroll
        for (int j = 0; j < 16; ++j) {
            float hpre = e0 * w1s[j] + e1 * w1s[16 + j] + e2 * w1s[32 + j] + e3 * w1s[48 + j] + b1s[j];
            float hg = 0.5f * hpre * (1.f + erff(hpre * 0.70710678f));
#pragma unroll
            for (int hh = 0; hh < 8; ++hh) g[hh] += hg * w2s[j * 8 + hh];
        }
#pragma unroll
        for (int hh = 0; hh < 8; ++hh)
            gate2[(((size_t)nb * 8 + hh) * 64 + q) * 64 + pk] = f2bf(mv ? g[hh] : 0.f);
    }
}

// ---------------- fused qkv-GEMM + attention (pipelined, counted-vmcnt) ----------------
// Per kt the vm issue order is pinned:
//   dma16(kt+1) | pin | loadB(kk1) | kk0 MFMA (vmcnt(4): B of prev half-step arrived)
//   | loadB(kt+1,kk0) | kk1 MFMA (vmcnt(3)) | vmcnt(3) + raw barrier.
// At each barrier the only outstanding vm ops are the 3 next B loads; the thread's own
// dma16 is older than B loads already waited on => staged buffer complete for all threads.
// Reads of Xs[buf^1] from kt-1 were lgkm-consumed before that barrier => no WAR race.
__global__ __launch_bounds__(512, 4) void fused_qkv_attn_kernel(const u16* __restrict__ xbf,
                                                                const u16* __restrict__ wqkvT,
                                                                const float* __restrict__ b_qkv,
                                                                const u16* __restrict__ sbias2,
                                                                const u16* __restrict__ gate2,
                                                                const float* __restrict__ gbl,
                                                                u16* __restrict__ xmid) {
    __shared__ __align__(16) u16 Xs[2][64 * 64];   // staged x K-tile (chunk-swizzled)
    __shared__ __align__(16) u16 QPs[2][64 * 72];  // Q, overlaid by P after QK^T (same wave+rows)
    __shared__ __align__(16) u16 Ks[2][64 * 72];
    __shared__ __align__(16) u16 VTs[2][64 * 72];
    __shared__ float gl[2][64], vbl[2][64];

    int tid = threadIdx.x;
    int bidf = blockIdx.x;
    int logical = (bidf & 7) * 512 + (bidf >> 3);  // bijective XCD chunk swizzle (4096 % 8 == 0)
    int hp = logical & 3, nb = (logical >> 2) & 511, b = logical >> 11;
    int wave = tid >> 6, lane = tid & 63, l15 = lane & 15, quad = lane >> 4;
    int hloc = wave >> 2;        // 0..1
    int h = hp * 2 + hloc;       // global head
    int nt = wave & 3;           // 16-col slice within head (GEMM) / q-row block (attn)
    int m0 = nt * 16;
    size_t blockrow = (size_t)(b * NTOK + nb * 64);

    // ---- staging addresses (64-row tile across 512 threads) ----
    int srow = tid >> 3;
    int jch = tid & 7;
    int js = jch ^ (srow & 7);
    const u16* gA = xbf + (blockrow + srow) * CC + js * 8;
    int sw = l15 & 7;

    // ---- B fragment pointers: n = sec*512 + h*64 + nt*16 + l15 ----
    const u16* gB0 = wqkvT + (size_t)(0 * 512 + h * 64 + nt * 16 + l15) * CC;
    const u16* gB1 = wqkvT + (size_t)(1 * 512 + h * 64 + nt * 16 + l15) * CC;
    const u16* gB2 = wqkvT + (size_t)(2 * 512 + h * 64 + nt * 16 + l15) * CC;
    float bq0 = b_qkv[0 * 512 + h * 64 + nt * 16 + l15];
    float bq1 = b_qkv[1 * 512 + h * 64 + nt * 16 + l15];
    float bq2 = b_qkv[2 * 512 + h * 64 + nt * 16 + l15];

    f32x4 accQ[4], accK[4], accV[4];
#pragma unroll
    for (int i = 0; i < 4; ++i) {
        accQ[i] = (f32x4){0.f, 0.f, 0.f, 0.f};
        accK[i] = (f32x4){0.f, 0.f, 0.f, 0.f};
        accV[i] = (f32x4){0.f, 0.f, 0.f, 0.f};
    }

    int koq = quad * 8;
    // ---- prologue: stage Xs[0], preload B(step0); own dma done at vmcnt(3); sync ----
    dma16(gA, &Xs[0][wave * 512]);
    asm volatile("" ::: "memory");
    bf16x8 c0 = bc8(*(const uint4*)(gB0 + koq));
    bf16x8 c1 = bc8(*(const uint4*)(gB1 + koq));
    bf16x8 c2 = bc8(*(const uint4*)(gB2 + koq));
    asm volatile("s_waitcnt vmcnt(3)" ::: "memory");
    __builtin_amdgcn_s_barrier();

#pragma unroll
    for (int kt = 0; kt < 8; ++kt) {
        int buf = kt & 1;
        if (kt < 7) {
            dma16(gA + (kt + 1) * 64, &Xs[buf ^ 1][wave * 512]);
            asm volatile("" ::: "memory");  // pin: dma16 precedes the B loads in vm queue
        }
        // prefetch B for kk=1 of this kt
        {
            int ko1 = kt * 64 + 32 + koq;
            bf16x8 n0 = bc8(*(const uint4*)(gB0 + ko1));
            bf16x8 n1 = bc8(*(const uint4*)(gB1 + ko1));
            bf16x8 n2 = bc8(*(const uint4*)(gB2 + ko1));
            {   // kk = 0
                int ch = (quad ^ sw) * 8;
                bf16x8 a0 = *(const bf16x8*)&Xs[buf][(0 * 16 + l15) * 64 + ch];
                bf16x8 a1 = *(const bf16x8*)&Xs[buf][(1 * 16 + l15) * 64 + ch];
                bf16x8 a2 = *(const bf16x8*)&Xs[buf][(2 * 16 + l15) * 64 + ch];
                bf16x8 a3 = *(const bf16x8*)&Xs[buf][(3 * 16 + l15) * 64 + ch];
                accQ[0] = __builtin_amdgcn_mfma_f32_16x16x32_bf16(a0, c0, accQ[0], 0, 0, 0);
                accK[0] = __builtin_amdgcn_mfma_f32_16x16x32_bf16(a0, c1, accK[0], 0, 0, 0);
                accV[0] = __builtin_amdgcn_mfma_f32_16x16x32_bf16(a0, c2, accV[0], 0, 0, 0);
                accQ[1] = __builtin_amdgcn_mfma_f32_16x16x32_bf16(a1, c0, accQ[1], 0, 0, 0);
                accK[1] = __builtin_amdgcn_mfma_f32_16x16x32_bf16(a1, c1, accK[1], 0, 0, 0);
                accV[1] = __builtin_amdgcn_mfma_f32_16x16x32_bf16(a1, c2, accV[1], 0, 0, 0);
                accQ[2] = __builtin_amdgcn_mfma_f32_16x16x32_bf16(a2, c0, accQ[2], 0, 0, 0);
                accK[2] = __builtin_amdgcn_mfma_f32_16x16x32_bf16(a2, c1, accK[2], 0, 0, 0);
                accV[2] = __builtin_amdgcn_mfma_f32_16x16x32_bf16(a2, c2, accV[2], 0, 0, 0);
                accQ[3] = __builtin_amdgcn_mfma_f32_16x16x32_bf16(a3, c0, accQ[3], 0, 0, 0);
                accK[3] = __builtin_amdgcn_mfma_f32_16x16x32_bf16(a3, c1, accK[3], 0, 0, 0);
                accV[3] = __builtin_amdgcn_mfma_f32_16x16x32_bf16(a3, c2, accV[3], 0, 0, 0);
            }
            c0 = n0; c1 = n1; c2 = n2;
        }
        // prefetch B for kk=0 of next kt
        if (kt < 7) {
            int ko2 = (kt + 1) * 64 + koq;
            bf16x8 n0 = bc8(*(const uint4*)(gB0 + ko2));
            bf16x8 n1 = bc8(*(const uint4*)(gB1 + ko2));
            bf16x8 n2 = bc8(*(const uint4*)(gB2 + ko2));
            {   // kk = 1
                int ch = ((4 + quad) ^ sw) * 8;
                bf16x8 a0 = *(const bf16x8*)&Xs[buf][(0 * 16 + l15) * 64 + ch];
                bf16x8 a1 = *(const bf16x8*)&Xs[buf][(1 * 16 + l15) * 64 + ch];
                bf16x8 a2 = *(const bf16x8*)&Xs[buf][(2 * 16 + l15) * 64 + ch];
                bf16x8 a3 = *(const bf16x8*)&Xs[buf][(3 * 16 + l15) * 64 + ch];
                accQ[0] = __builtin_amdgcn_mfma_f32_16x16x32_bf16(a0, c0, accQ[0], 0, 0, 0);
                accK[0] = __builtin_amdgcn_mfma_f32_16x16x32_bf16(a0, c1, accK[0], 0, 0, 0);
                accV[0] = __builtin_amdgcn_mfma_f32_16x16x32_bf16(a0, c2, accV[0], 0, 0, 0);
                accQ[1] = __builtin_amdgcn_mfma_f32_16x16x32_bf16(a1, c0, accQ[1], 0, 0, 0);
                accK[1] = __builtin_amdgcn_mfma_f32_16x16x32_bf16(a1, c1, accK[1], 0, 0, 0);
                accV[1] = __builtin_amdgcn_mfma_f32_16x16x32_bf16(a1, c2, accV[1], 0, 0, 0);
                accQ[2] = __builtin_amdgcn_mfma_f32_16x16x32_bf16(a2, c0, accQ[2], 0, 0, 0);
                accK[2] = __builtin_amdgcn_mfma_f32_16x16x32_bf16(a2, c1, accK[2], 0, 0, 0);
                accV[2] = __builtin_amdgcn_mfma_f32_16x16x32_bf16(a2, c2, accV[2], 0, 0, 0);
                accQ[3] = __builtin_amdgcn_mfma_f32_16x16x32_bf16(a3, c0, accQ[3], 0, 0, 0);
                accK[3] = __builtin_amdgcn_mfma_f32_16x16x32_bf16(a3, c1, accK[3], 0, 0, 0);
                accV[3] = __builtin_amdgcn_mfma_f32_16x16x32_bf16(a3, c2, accV[3], 0, 0, 0);
            }
            c0 = n0; c1 = n1; c2 = n2;
            asm volatile("s_waitcnt vmcnt(3)" ::: "memory");  // dma16(kt+1) (older) complete
            __builtin_amdgcn_s_barrier();
        } else {
            // final kk = 1 (no further prefetch)
            int ch = ((4 + quad) ^ sw) * 8;
            bf16x8 a0 = *(const bf16x8*)&Xs[buf][(0 * 16 + l15) * 64 + ch];
            bf16x8 a1 = *(const bf16x8*)&Xs[buf][(1 * 16 + l15) * 64 + ch];
            bf16x8 a2 = *(const bf16x8*)&Xs[buf][(2 * 16 + l15) * 64 + ch];
            bf16x8 a3 = *(const bf16x8*)&Xs[buf][(3 * 16 + l15) * 64 + ch];
            accQ[0] = __builtin_amdgcn_mfma_f32_16x16x32_bf16(a0, c0, accQ[0], 0, 0, 0);
            accK[0] = __builtin_amdgcn_mfma_f32_16x16x32_bf16(a0, c1, accK[0], 0, 0, 0);
            accV[0] = __builtin_amdgcn_mfma_f32_16x16x32_bf16(a0, c2, accV[0], 0, 0, 0);
            accQ[1] = __builtin_amdgcn_mfma_f32_16x16x32_bf16(a1, c0, accQ[1], 0, 0, 0);
            accK[1] = __builtin_amdgcn_mfma_f32_16x16x32_bf16(a1, c1, accK[1], 0, 0, 0);
            accV[1] = __builtin_amdgcn_mfma_f32_16x16x32_bf16(a1, c2, accV[1], 0, 0, 0);
            accQ[2] = __builtin_amdgcn_mfma_f32_16x16x32_bf16(a2, c0, accQ[2], 0, 0, 0);
            accK[2] = __builtin_amdgcn_mfma_f32_16x16x32_bf16(a2, c1, accK[2], 0, 0, 0);
            accV[2] = __builtin_amdgcn_mfma_f32_16x16x32_bf16(a2, c2, accV[2], 0, 0, 0);
            accQ[3] = __builtin_amdgcn_mfma_f32_16x16x32_bf16(a3, c0, accQ[3], 0, 0, 0);
            accK[3] = __builtin_amdgcn_mfma_f32_16x16x32_bf16(a3, c1, accK[3], 0, 0, 0);
            accV[3] = __builtin_amdgcn_mfma_f32_16x16x32_bf16(a3, c2, accV[3], 0, 0, 0);
        }
    }

    // ---- prefetch softmax bias + gate fragments (hide L2 latency under epilogue+QK^T) ----
    ushort4 svp[4], gvp[4];
    {
        const u16* sb2 = sbias2 + (size_t)nb * 4096;
        const u16* gp2 = gate2 + ((size_t)nb * 8 + h) * 4096;
#pragma unroll
        for (int r = 0; r < 4; ++r) {
            int q = m0 + quad * 4 + r;
            svp[r] = *(const ushort4*)(sb2 + (q * 16 + l15) * 4);
            gvp[r] = *(const ushort4*)(gp2 + (q * 16 + l15) * 4);
        }
    }

    // ---- write Q/K/V to LDS in attention layouts ----
    {
        int dloc = nt * 16 + l15;
#pragma unroll
        for (int i = 0; i < 4; ++i) {
#pragma unroll
            for (int r = 0; r < 4; ++r) {
                int tok = i * 16 + quad * 4 + r;
                QPs[hloc][tok * 72 + dloc] = f2bf(accQ[i][r] + bq0);
                Ks[hloc][tok * 72 + dloc] = f2bf(accK[i][r] + bq1);
                VTs[hloc][dloc * 72 + tok] = f2bf(accV[i][r] + bq2);
            }
        }
    }
    if (tid < 128) {
        int hl = tid >> 6, tok = tid & 63;
        gl[hl][tok] = gbl[(blockrow + tok) * 8 + hp * 2 + hl];
    }
    __syncthreads();

    if (tid < 128) {
        int hl = tid >> 6, d = tid & 63;
        float s = 0.f;
#pragma unroll 8
        for (int k = 0; k < 64; ++k) s += bf2f(VTs[hl][d * 72 + k]);
        vbl[hl][d] = s * 0.015625f;
    }

    // ---- QK^T ----
    f32x4 sc[4];
#pragma unroll
    for (int t = 0; t < 4; ++t) sc[t] = (f32x4){0.f, 0.f, 0.f, 0.f};
#pragma unroll
    for (int kk = 0; kk < 2; ++kk) {
        bf16x8 a = *(const bf16x8*)&QPs[hloc][(m0 + l15) * 72 + kk * 32 + quad * 8];
#pragma unroll
        for (int t = 0; t < 4; ++t) {
            bf16x8 bb = *(const bf16x8*)&Ks[hloc][(t * 16 + l15) * 72 + kk * 32 + quad * 8];
            sc[t] = __builtin_amdgcn_mfma_f32_16x16x32_bf16(a, bb, sc[t], 0, 0, 0);
        }
    }
    // ---- softmax + gate, P written over Q's LDS (same wave, same rows) ----
    {
#pragma unroll
        for (int r = 0; r < 4; ++r) {
            int q = m0 + quad * 4 + r;
            ushort4 sv = svp[r];
            float bias_t[4] = {bf2f(sv.x), bf2f(sv.y), bf2f(sv.z), bf2f(sv.w)};
            float mx = -3e38f;
#pragma unroll
            for (int t = 0; t < 4; ++t) {
                float v = sc[t][r] * 0.125f + bias_t[t];
                sc[t][r] = v;
                mx = fmaxf(mx, v);
            }
            mx = fmaxf(mx, __shfl_xor(mx, 1));
            mx = fmaxf(mx, __shfl_xor(mx, 2));
            mx = fmaxf(mx, __shfl_xor(mx, 4));
            mx = fmaxf(mx, __shfl_xor(mx, 8));
            float sum = 0.f;
#pragma unroll
            for (int t = 0; t < 4; ++t) {
                float p = __expf(sc[t][r] - mx);
                sc[t][r] = p;
                sum += p;
            }
            sum += __shfl_xor(sum, 1);
            sum += __shfl_xor(sum, 2);
            sum += __shfl_xor(sum, 4);
            sum += __shfl_xor(sum, 8);
            float inv = 1.f / sum;
            ushort4 gv = gvp[r];
            float gate_t[4] = {bf2f(gv.x), bf2f(gv.y), bf2f(gv.z), bf2f(gv.w)};
#pragma unroll
            for (int t = 0; t < 4; ++t) {
                float comb = sc[t][r] * inv + gate_t[t];
                QPs[hloc][q * 72 + t * 16 + l15] = f2bf(comb);
            }
        }
    }
    __syncthreads();

    // ---- PV ----
    f32x4 o[4];
#pragma unroll
    for (int t = 0; t < 4; ++t) o[t] = (f32x4){0.f, 0.f, 0.f, 0.f};
#pragma unroll
    for (int kk = 0; kk < 2; ++kk) {
        bf16x8 a = *(const bf16x8*)&QPs[hloc][(m0 + l15) * 72 + kk * 32 + quad * 8];
#pragma unroll
        for (int t = 0; t < 4; ++t) {
            bf16x8 bb = *(const bf16x8*)&VTs[hloc][(t * 16 + l15) * 72 + kk * 32 + quad * 8];
            o[t] = __builtin_amdgcn_mfma_f32_16x16x32_bf16(a, bb, o[t], 0, 0, 0);
        }
    }
#pragma unroll
    for (int t = 0; t < 4; ++t) {
#pragma unroll
        for (int r = 0; r < 4; ++r) {
            int q = m0 + quad * 4 + r, d = t * 16 + l15;
            float v = o[t][r] + gl[hloc][q] * vbl[hloc][d];
            xmid[(blockrow + q) * CC + h * 64 + d] = f2bf(v);
        }
    }
}

// ---------------- out = x_mid @ w_proj + b_proj (fp32 out) ----------------
__global__ __launch_bounds__(256) void outproj_kernel(const u16* __restrict__ xmid,
                                                      const u16* __restrict__ wprojT,
                                                      const float* __restrict__ b_proj,
                                                      float* __restrict__ out) {
    __shared__ __align__(16) u16 As[128 * 64], Bs[128 * 64];
    int tid = threadIdx.x;
    int flat = blockIdx.x;                     // 2048 blocks
    int logical = (flat & 7) * 256 + (flat >> 3);
    int n0 = (logical & 3) * 128;
    int m0 = (logical >> 2) * 128;
    int lane = tid & 63, l15 = lane & 15, quad = lane >> 4, wave = tid >> 6;
    int r8 = lane >> 3, jch = lane & 7;
    int js = jch ^ r8;
    int mwl = (wave >> 1) * 64, nwl = (wave & 1) * 64;
    int sw = l15 & 7;

    f32x4 acc[4][4];
#pragma unroll
    for (int i = 0; i < 4; ++i)
#pragma unroll
        for (int j = 0; j < 4; ++j) acc[i][j] = (f32x4){0.f, 0.f, 0.f, 0.f};

    int arow[4], brow[4];
#pragma unroll
    for (int i = 0; i < 4; ++i) arow[i] = (mwl + i * 16 + l15) * 64;
#pragma unroll
    for (int j = 0; j < 4; ++j) brow[j] = (nwl + j * 16 + l15) * 64;

    const u16* gA = xmid + (size_t)(m0 + wave * 32 + r8) * CC + js * 8;
    const u16* gB = wprojT + (size_t)(n0 + wave * 32 + r8) * CC + js * 8;
    u16* lA = As + wave * 32 * 64;
    u16* lB = Bs + wave * 32 * 64;

    for (int kt = 0; kt < 8; ++kt) {
        int k0 = kt * 64;
#pragma unroll
        for (int t = 0; t < 4; ++t) {
            dma16(gA + (size_t)t * 8 * CC + k0, lA + t * 8 * 64);
            dma16(gB + (size_t)t * 8 * CC + k0, lB + t * 8 * 64);
        }
        __syncthreads();
#pragma unroll
        for (int kk = 0; kk < 2; ++kk) {
            int ch = ((kk * 4 + quad) ^ sw) * 8;
            bf16x8 a[4], bb[4];
#pragma unroll
            for (int i = 0; i < 4; ++i) a[i] = *(const bf16x8*)&As[arow[i] + ch];
#pragma unroll
            for (int j = 0; j < 4; ++j) bb[j] = *(const bf16x8*)&Bs[brow[j] + ch];
#pragma unroll
            for (int i = 0; i < 4; ++i)
#pragma unroll
                for (int j = 0; j < 4; ++j)
                    acc[i][j] = __builtin_amdgcn_mfma_f32_16x16x32_bf16(a[i], bb[j], acc[i][j], 0, 0, 0);
        }
        __syncthreads();
    }
#pragma unroll
    for (int i = 0; i < 4; ++i)
#pragma unroll
        for (int j = 0; j < 4; ++j) {
            int col = n0 + nwl + j * 16 + l15;
            float bp = b_proj[col];
#pragma unroll
            for (int r = 0; r < 4; ++r) {
                int row = m0 + mwl + i * 16 + quad * 4 + r;
                out[(size_t)row * CC + col] = acc[i][j][r] + bp;
            }
        }
}

extern "C" void kernel_launch(void* const* d_in, const int* in_sizes, int n_in,
                              void* d_out, int out_size, void* d_ws, size_t ws_size,
                              hipStream_t stream) {
    const float* x = (const float*)d_in[0];
    const int* attn_mask = (const int*)d_in[1];
    const float* edge = (const float*)d_in[2];
    const float* w_qkv = (const float*)d_in[3];
    const float* b_qkv = (const float*)d_in[4];
    const float* w_proj = (const float*)d_in[5];
    const float* b_proj = (const float*)d_in[6];
    const float* w_eg1 = (const float*)d_in[7];
    const float* b_eg1 = (const float*)d_in[8];
    const float* w_eg2 = (const float*)d_in[9];
    const float* b_eg2 = (const float*)d_in[10];
    const float* w_blk = (const float*)d_in[11];
    const float* b_blk = (const float*)d_in[12];
    float* out = (float*)d_out;

    char* ws = (char*)d_ws;
    u16* xbf = (u16*)ws;                            // 67108864 bytes
    u16* xmid = (u16*)(ws + 67108864);              // 67108864
    u16* gate2 = (u16*)(ws + 268435456);            // 33554432
    u16* sbias2 = (u16*)(ws + 301989888);           // 4194304
    u16* wqkvT = (u16*)(ws + 306184192);            // 1572864
    u16* wprojT = (u16*)(ws + 307757056);           // 524288
    float* gbl = (float*)(ws + 308281344);          // 2097152

    convert_gblock_kernel<<<16384, 256, 0, stream>>>(x, xbf, w_blk, b_blk, gbl);
    transpose_bf16_kernel<<<dim3(48, 16), 256, 0, stream>>>(w_qkv, wqkvT, 512, 1536);
    transpose_bf16_kernel<<<dim3(16, 16), 256, 0, stream>>>(w_proj, wprojT, 512, 512);
    gate_sbias_kernel<<<2048, 256, 0, stream>>>(attn_mask, edge, w_eg1, b_eg1, w_eg2, b_eg2,
                                                gate2, sbias2);
    fused_qkv_attn_kernel<<<4096, 512, 0, stream>>>(xbf, wqkvT, b_qkv, sbias2, gate2, gbl, xmid);
    outproj_kernel<<<2048, 256, 0, stream>>>(xmid, wprojT, b_proj, out);
}